// Round 10
// baseline (194.873 us; speedup 1.0000x reference)
//
#include <hip/hip_runtime.h>
#include <hip/hip_bf16.h>
#include <hip/hip_fp16.h>

#define NN   102400
#define NG   64
#define NPG  1600
#define NE   1638400
#define EPG  25600
#define EPC  (EPG / 4)   // 6400 edges per chunk (hist/scatter)

typedef unsigned int u32;
typedef unsigned short u16;

struct H8 { __half2 a, b, c, d; };
struct H4 { __half2 a, b; };

__device__ __forceinline__ void unpack8(const H8 v, float* o) {
    float2 t0 = __half22float2(v.a), t1 = __half22float2(v.b);
    float2 t2 = __half22float2(v.c), t3 = __half22float2(v.d);
    o[0]=t0.x; o[1]=t0.y; o[2]=t1.x; o[3]=t1.y; o[4]=t2.x; o[5]=t2.y; o[6]=t3.x; o[7]=t3.y;
}
__device__ __forceinline__ H8 pack8(const float* v) {
    H8 r;
    r.a = __floats2half2_rn(v[0], v[1]); r.b = __floats2half2_rn(v[2], v[3]);
    r.c = __floats2half2_rn(v[4], v[5]); r.d = __floats2half2_rn(v[6], v[7]);
    return r;
}
__device__ __forceinline__ H4 pack4(const float* v) {
    H4 r;
    r.a = __floats2half2_rn(v[0], v[1]); r.b = __floats2half2_rn(v[2], v[3]);
    return r;
}
__device__ __forceinline__ u16 f2bf(float f) {
    u32 u = __float_as_uint(f);
    return (u16)((u + 0x7fffu + ((u >> 16) & 1u)) >> 16);
}
__device__ __forceinline__ float wsum(float v) {
#pragma unroll
    for (int o = 32; o >= 1; o >>= 1) v += __shfl_xor(v, o);
    return v;
}
__device__ __forceinline__ float wsum_par(float v) {
#pragma unroll
    for (int o = 2; o <= 32; o <<= 1) v += __shfl_xor(v, o);
    return v;
}
__device__ __forceinline__ float sigmoidf_(float x) { return 1.f / (1.f + expf(-x)); }

// ============================ SHARED KERNELS ============================

// per-chunk histogram over idx[] (rcv or snd), LDS atomics, plain stores.
__global__ __launch_bounds__(512) void k_hist4(const int* __restrict__ idx, int* __restrict__ h4) {
    __shared__ int h[NPG];
    const int g = blockIdx.x >> 2, c = blockIdx.x & 3;
    for (int i = threadIdx.x; i < NPG; i += 512) h[i] = 0;
    __syncthreads();
    const int base = g * EPG + c * EPC;
    for (int t = threadIdx.x; t < EPC; t += 512) atomicAdd(&h[idx[base + t] - g * NPG], 1);
    __syncthreads();
    int* out = h4 + (size_t)(g * 4 + c) * NPG;
    for (int i = threadIdx.x; i < NPG; i += 512) out[i] = h[i];
}

// scan with GLOBAL offsets (start & cursor bases include g*EPG).
__global__ __launch_bounds__(320) void k_scan(
    int* __restrict__ h4c, int* __restrict__ deg, int* __restrict__ start)
{
    __shared__ int part[320];
    const int g = blockIdx.x, tid = threadIdx.x;
    const int vb = tid * 5;
    int hc[5][4], d[5], pre[5];
    int ts = 0;
#pragma unroll
    for (int i = 0; i < 5; ++i) {
        const int v = vb + i;
#pragma unroll
        for (int c = 0; c < 4; ++c) hc[i][c] = h4c[(size_t)(g * 4 + c) * NPG + v];
        d[i] = hc[i][0] + hc[i][1] + hc[i][2] + hc[i][3];
        pre[i] = ts;
        ts += d[i];
    }
    part[tid] = ts;
    __syncthreads();
    for (int o = 1; o < 320; o <<= 1) {
        const int v = (tid >= o) ? part[tid - o] : 0;
        __syncthreads();
        part[tid] += v;
        __syncthreads();
    }
    const int off = g * EPG + part[tid] - ts;
#pragma unroll
    for (int i = 0; i < 5; ++i) {
        const int v = vb + i;
        const int st = off + pre[i];
        deg[g * NPG + v] = d[i];
        start[g * NPG + v] = st;
        int run = st;
#pragma unroll
        for (int c = 0; c < 4; ++c) {
            h4c[(size_t)(g * 4 + c) * NPG + v] = run;
            run += hc[i][c];
        }
    }
}

// scan with LOCAL offsets (start & cursor bases in [0, EPG)).
__global__ __launch_bounds__(320) void n_scan_local(
    int* __restrict__ h4c, int* __restrict__ deg, int* __restrict__ startL)
{
    __shared__ int part[320];
    const int g = blockIdx.x, tid = threadIdx.x;
    const int vb = tid * 5;
    int hc[5][4], d[5], pre[5];
    int ts = 0;
#pragma unroll
    for (int i = 0; i < 5; ++i) {
        const int v = vb + i;
#pragma unroll
        for (int c = 0; c < 4; ++c) hc[i][c] = h4c[(size_t)(g * 4 + c) * NPG + v];
        d[i] = hc[i][0] + hc[i][1] + hc[i][2] + hc[i][3];
        pre[i] = ts;
        ts += d[i];
    }
    part[tid] = ts;
    __syncthreads();
    for (int o = 1; o < 320; o <<= 1) {
        const int v = (tid >= o) ? part[tid - o] : 0;
        __syncthreads();
        part[tid] += v;
        __syncthreads();
    }
    const int off = part[tid] - ts;   // LOCAL
#pragma unroll
    for (int i = 0; i < 5; ++i) {
        const int v = vb + i;
        const int st = off + pre[i];
        deg[g * NPG + v] = d[i];
        startL[g * NPG + v] = st;
        int run = st;
#pragma unroll
        for (int c = 0; c < 4; ++c) {
            h4c[(size_t)(g * 4 + c) * NPG + v] = run;
            run += hc[i][c];
        }
    }
}

// encoder global layer + g1 projections for hidden layers.
__global__ void k_glob_enc(
    const float* __restrict__ esum1, const float* __restrict__ nsum1,
    const float* __restrict__ Wge, const float* __restrict__ Wgn, const float* __restrict__ bg,
    const float* __restrict__ hWeg, const float* __restrict__ hWng,
    float* __restrict__ g1, float* __restrict__ gpe, float* __restrict__ gpn)
{
    const int g = threadIdx.x;
    if (g >= NG) return;
    float gv[4];
#pragma unroll
    for (int o = 0; o < 4; ++o) {
        float x = bg[o];
#pragma unroll
        for (int k = 0; k < 8; ++k)  x = fmaf(esum1[g * 8 + k] * (1.f / EPG), Wge[o * 8 + k], x);
#pragma unroll
        for (int k = 0; k < 16; ++k) x = fmaf(nsum1[g * 16 + k] * (1.f / NPG), Wgn[o * 16 + k], x);
        gv[o] = fmaxf(0.f, x);
        g1[g * 4 + o] = gv[o];
    }
#pragma unroll
    for (int j = 0; j < 8; ++j) {
        float x = 0.f;
#pragma unroll
        for (int o = 0; o < 4; ++o) x = fmaf(gv[o], hWeg[j * 4 + o], x);
        gpe[g * 8 + j] = x;
    }
#pragma unroll
    for (int j = 0; j < 16; ++j) {
        float x = 0.f;
#pragma unroll
        for (int o = 0; o < 4; ++o) x = fmaf(gv[o], hWng[j * 4 + o], x);
        gpn[g * 16 + j] = x;
    }
}

// hidden global layer + global readout.
__global__ void k_glob_hid(
    const float* __restrict__ esum2, const float* __restrict__ nsum2, const float* __restrict__ g1,
    const float* __restrict__ hWge, const float* __restrict__ hWgn,
    const float* __restrict__ hWgg, const float* __restrict__ hbg,
    const float* __restrict__ roWg, const float* __restrict__ robg,
    float* __restrict__ outg)
{
    const int g = threadIdx.x;
    if (g >= NG) return;
    float gv[4];
#pragma unroll
    for (int o = 0; o < 4; ++o) {
        float x = hbg[o];
#pragma unroll
        for (int k = 0; k < 8; ++k)  x = fmaf(esum2[g * 8 + k] * (1.f / EPG), hWge[o * 8 + k], x);
#pragma unroll
        for (int k = 0; k < 16; ++k) x = fmaf(nsum2[g * 16 + k] * (1.f / NPG), hWgn[o * 16 + k], x);
#pragma unroll
        for (int k = 0; k < 4; ++k)  x = fmaf(g1[g * 4 + k], hWgg[o * 4 + k], x);
        gv[o] = fmaxf(0.f, x);
    }
    float z = robg[0];
#pragma unroll
    for (int o = 0; o < 4; ++o) z = fmaf(gv[o], roWg[o], z);
    outg[g] = sigmoidf_(z);
}

// ============================ NEW PATH (sender-major scatter-store) ============================
// ws layout (floats): edat_s[NE] | deg_r[NN] startL_r[NN] deg_s[NN] start_s[NN] |
//                     sprojA[NN*4] | pnn[NN*8] | gs[4864] | POOL (4*NE floats):
//                     setup: rpos[NE] h4c_r[4NN] h4c_s[4NN]; compute: evals f16[NE*8]
#define P2_EDATS  0
#define P2_DEGR   (NE)
#define P2_STARTR (NE + NN)
#define P2_DEGS   (NE + 2 * NN)
#define P2_STARTS (NE + 3 * NN)
#define P2_SPROJA (NE + 4 * NN)
#define P2_PNN    (NE + 8 * NN)
#define P2_GS     (NE + 16 * NN)
#define P2_POOL   (NE + 16 * NN + 4864)
#define P2_NEED_BYTES ((size_t)(P2_POOL + 4 * NE) * 4)

// scatter receiver positions (local) per original edge.
__global__ __launch_bounds__(512) void n_scat_rpos(
    const int* __restrict__ rcv, const int* __restrict__ h4c_r, int* __restrict__ rpos)
{
    __shared__ int cur[NPG];
    const int g = blockIdx.x >> 2, c = blockIdx.x & 3;
    const int* cb = h4c_r + (size_t)(g * 4 + c) * NPG;
    for (int i = threadIdx.x; i < NPG; i += 512) cur[i] = cb[i];
    __syncthreads();
    const int base = g * EPG + c * EPC;
    for (int t = threadIdx.x; t < EPC; t += 512) {
        const int e = base + t;
        const int r = rcv[e] - g * NPG;
        rpos[e] = atomicAdd(&cur[r], 1);
    }
}

// scatter (rpos<<16)|bf16(ef) into sender-sorted order.
__global__ __launch_bounds__(512) void n_scat_s(
    const float* __restrict__ ef, const int* __restrict__ snd,
    const int* __restrict__ rpos, const int* __restrict__ h4c_s, u32* __restrict__ edat_s)
{
    __shared__ int cur[NPG];
    const int g = blockIdx.x >> 2, c = blockIdx.x & 3;
    const int* cb = h4c_s + (size_t)(g * 4 + c) * NPG;
    for (int i = threadIdx.x; i < NPG; i += 512) cur[i] = cb[i];
    __syncthreads();
    const int base = g * EPG + c * EPC;
    for (int t = threadIdx.x; t < EPC; t += 512) {
        const int e = base + t;
        const int s = snd[e] - g * NPG;
        const int p = atomicAdd(&cur[s], 1);
        edat_s[p] = ((u32)rpos[e] << 16) | (u32)f2bf(ef[e]);
    }
}

// node pre-projections: sprojA = nf@Wes^T + ebe (8ch), pnn = nf@Wnn^T + ebn (16ch); zero gs.
__global__ __launch_bounds__(256) void n_node_pre(
    const float* __restrict__ nf,
    const float* __restrict__ Wes, const float* __restrict__ Wnn,
    const float* __restrict__ ebe, const float* __restrict__ ebn,
    __half* __restrict__ sprojA, __half* __restrict__ pnn, float* __restrict__ gs)
{
    __shared__ float wE[480], wN[960];
    for (int i = threadIdx.x; i < 480; i += 256) wE[i] = Wes[i];
    for (int i = threadIdx.x; i < 960; i += 256) wN[i] = Wnn[i];
    if (blockIdx.x == 0) {
        for (int i = threadIdx.x; i < 3072; i += 256) gs[i] = 0.f;
    }
    __syncthreads();
    const int v = blockIdx.x * 256 + threadIdx.x;
    const float4* row = reinterpret_cast<const float4*>(nf + (size_t)v * 60);
    float x[60];
#pragma unroll
    for (int i = 0; i < 15; ++i) {
        const float4 a = row[i];
        x[4 * i] = a.x; x[4 * i + 1] = a.y; x[4 * i + 2] = a.z; x[4 * i + 3] = a.w;
    }
    float pes[8], pn[16];
#pragma unroll
    for (int j = 0; j < 8; ++j) pes[j] = ebe[j];
#pragma unroll
    for (int j = 0; j < 16; ++j) pn[j] = ebn[j];
#pragma unroll
    for (int k = 0; k < 60; ++k) {
        const float xv = x[k];
#pragma unroll
        for (int j = 0; j < 8; ++j)  pes[j] = fmaf(xv, wE[j * 60 + k], pes[j]);
#pragma unroll
        for (int j = 0; j < 16; ++j) pn[j]  = fmaf(xv, wN[j * 60 + k], pn[j]);
    }
    reinterpret_cast<H8*>(sprojA)[v] = pack8(pes);
    H8* pp = reinterpret_cast<H8*>(pnn) + (size_t)v * 2;
    pp[0] = pack8(pn); pp[1] = pack8(pn + 8);
}

// A1: encoder edge compute, sender-major, scatter-store to evals.
__global__ __launch_bounds__(256) void n_a1(
    const int* __restrict__ deg_s, const int* __restrict__ start_s,
    const u32* __restrict__ edat_s, const __half* __restrict__ sprojA,
    const float* __restrict__ eWee, __half* __restrict__ evals)
{
    const int v = blockIdx.x * 256 + threadIdx.x;
    const int g = v / NPG;
    float wee[8];
#pragma unroll
    for (int j = 0; j < 8; ++j) wee[j] = eWee[j];
    float ps[8];
    unpack8(reinterpret_cast<const H8*>(sprojA)[v], ps);
    const int dg = deg_s[v];
    const int st = start_s[v];
    H8* ev = reinterpret_cast<H8*>(evals) + (size_t)g * EPG;
    for (int i = 0; i < dg; ++i) {
        const u32 w = edat_s[st + i];
        const float f = __uint_as_float((w & 0xffffu) << 16);
        const int rp = (int)(w >> 16);
        float c[8];
#pragma unroll
        for (int j = 0; j < 8; ++j) c[j] = fmaxf(0.f, fmaf(f, wee[j], ps[j]));
        ev[rp] = pack8(c);
    }
}

// B1: encoder node layer, receiver-major, coalesced evals reads; n1 -> pnn.
__global__ __launch_bounds__(256) void n_b1(
    const int* __restrict__ deg_r, const int* __restrict__ startL_r,
    const __half* __restrict__ evals, __half* __restrict__ pnn,
    const float* __restrict__ eWni,
    float* __restrict__ esum, float* __restrict__ nsum)
{
    __shared__ float wNI[128];
    for (int i = threadIdx.x; i < 128; i += 256) wNI[i] = eWni[i];
    __syncthreads();
    const int v = blockIdx.x * 256 + threadIdx.x;
    const int g = v / NPG;
    const int dg = deg_r[v];
    const H8* ev = reinterpret_cast<const H8*>(evals) + (size_t)g * EPG + startL_r[v];
    float m[8];
#pragma unroll
    for (int j = 0; j < 8; ++j) m[j] = 0.f;
    for (int i = 0; i < dg; ++i) {
        float t[8]; unpack8(ev[i], t);
#pragma unroll
        for (int j = 0; j < 8; ++j) m[j] += t[j];
    }
#pragma unroll
    for (int j = 0; j < 8; ++j) {
        const float s = wsum(m[j]);
        if ((threadIdx.x & 63) == 0) atomicAdd(&esum[g * 8 + j], s);
    }
    const float ic = 1.f / fmaxf((float)dg, 1.f);
    float mk[8];
#pragma unroll
    for (int k = 0; k < 8; ++k) mk[k] = m[k] * ic;
    H8* pp = reinterpret_cast<H8*>(pnn) + (size_t)v * 2;
    float pn[16]; unpack8(pp[0], pn); unpack8(pp[1], pn + 8);
    float n1[16];
#pragma unroll
    for (int j = 0; j < 16; ++j) {
        float x = pn[j];
#pragma unroll
        for (int k = 0; k < 8; ++k) x = fmaf(mk[k], wNI[j * 8 + k], x);
        n1[j] = fmaxf(0.f, x);
    }
    pp[0] = pack8(n1); pp[1] = pack8(n1 + 8);
#pragma unroll
    for (int j = 0; j < 16; ++j) {
        const float s = wsum(n1[j]);
        if ((threadIdx.x & 63) == 0) atomicAdd(&nsum[g * 16 + j], s);
    }
}

// A2: hidden edge compute, sender-major (recompute e1, pes2 from n1), scatter-store.
__global__ __launch_bounds__(256) void n_a2(
    const int* __restrict__ deg_s, const int* __restrict__ start_s,
    const u32* __restrict__ edat_s, const __half* __restrict__ sprojA,
    const __half* __restrict__ pnn,   // n1
    const float* __restrict__ eWee, const float* __restrict__ hWes,
    const float* __restrict__ hWee, const float* __restrict__ hbe,
    const float* __restrict__ gpe, __half* __restrict__ evals)
{
    __shared__ float wES[128], w2[64];
    for (int i = threadIdx.x; i < 128; i += 256) wES[i] = hWes[i];
    if (threadIdx.x < 64) w2[threadIdx.x] = hWee[threadIdx.x];
    __syncthreads();
    const int v = blockIdx.x * 256 + threadIdx.x;
    const int g = v / NPG;
    float wee[8];
#pragma unroll
    for (int j = 0; j < 8; ++j) wee[j] = eWee[j];
    float ps[8];
    unpack8(reinterpret_cast<const H8*>(sprojA)[v], ps);
    const H8* pp = reinterpret_cast<const H8*>(pnn) + (size_t)v * 2;
    float n1[16]; unpack8(pp[0], n1); unpack8(pp[1], n1 + 8);
    float pe[8];
#pragma unroll
    for (int o = 0; o < 8; ++o) {
        float x = gpe[g * 8 + o] + hbe[o];
#pragma unroll
        for (int j = 0; j < 16; ++j) x = fmaf(n1[j], wES[o * 16 + j], x);
        pe[o] = x;
    }
    const int dg = deg_s[v];
    const int st = start_s[v];
    H8* ev = reinterpret_cast<H8*>(evals) + (size_t)g * EPG;
    for (int i = 0; i < dg; ++i) {
        const u32 w = edat_s[st + i];
        const float f = __uint_as_float((w & 0xffffu) << 16);
        const int rp = (int)(w >> 16);
        float e1[8];
#pragma unroll
        for (int j = 0; j < 8; ++j) e1[j] = fmaxf(0.f, fmaf(f, wee[j], ps[j]));
        float c[8];
#pragma unroll
        for (int j = 0; j < 8; ++j) {
            float x = pe[j];
#pragma unroll
            for (int k = 0; k < 8; ++k) x = fmaf(e1[k], w2[j * 8 + k], x);
            c[j] = fmaxf(0.f, x);
        }
        ev[rp] = pack8(c);
    }
}

// B2: hidden node layer + readout, receiver-major, coalesced evals reads.
__global__ __launch_bounds__(256) void n_b2(
    const int* __restrict__ deg_r, const int* __restrict__ startL_r,
    const __half* __restrict__ evals, const __half* __restrict__ pnn,  // n1
    const float* __restrict__ hWnn, const float* __restrict__ hWni,
    const float* __restrict__ hbn, const float* __restrict__ gpn,
    const float* __restrict__ roWn, const float* __restrict__ robn,
    float* __restrict__ esum, float* __restrict__ nsum, float* __restrict__ outn)
{
    __shared__ float wNN[256], wNI[128], rW[16];
    wNN[threadIdx.x] = hWnn[threadIdx.x];
    for (int i = threadIdx.x; i < 128; i += 256) wNI[i] = hWni[i];
    if (threadIdx.x < 16) rW[threadIdx.x] = roWn[threadIdx.x];
    __syncthreads();
    const int v = blockIdx.x * 256 + threadIdx.x;
    const int g = v / NPG;
    const int dg = deg_r[v];
    const H8* ev = reinterpret_cast<const H8*>(evals) + (size_t)g * EPG + startL_r[v];
    float m2[8];
#pragma unroll
    for (int j = 0; j < 8; ++j) m2[j] = 0.f;
    for (int i = 0; i < dg; ++i) {
        float t[8]; unpack8(ev[i], t);
#pragma unroll
        for (int j = 0; j < 8; ++j) m2[j] += t[j];
    }
#pragma unroll
    for (int j = 0; j < 8; ++j) {
        const float s = wsum(m2[j]);
        if ((threadIdx.x & 63) == 0) atomicAdd(&esum[g * 8 + j], s);
    }
    const float ic = 1.f / fmaxf((float)dg, 1.f);
    float mk[8];
#pragma unroll
    for (int k = 0; k < 8; ++k) mk[k] = m2[k] * ic;
    const H8* pp = reinterpret_cast<const H8*>(pnn) + (size_t)v * 2;
    float n1[16]; unpack8(pp[0], n1); unpack8(pp[1], n1 + 8);
    float z = robn[0];
    float n2[16];
#pragma unroll
    for (int j = 0; j < 16; ++j) {
        float x = gpn[g * 16 + j] + hbn[j];
#pragma unroll
        for (int k = 0; k < 16; ++k) x = fmaf(n1[k], wNN[j * 16 + k], x);
#pragma unroll
        for (int k = 0; k < 8; ++k)  x = fmaf(mk[k], wNI[j * 8 + k], x);
        n2[j] = fmaxf(0.f, x);
        z = fmaf(n2[j], rW[j], z);
    }
    outn[v] = sigmoidf_(z);
#pragma unroll
    for (int j = 0; j < 16; ++j) {
        const float s = wsum(n2[j]);
        if ((threadIdx.x & 63) == 0) atomicAdd(&nsum[g * 16 + j], s);
    }
}

// ============================ OLD PATH (R8, proven 144 us, 15.6 MB ws) ============================
#define OFF_EDAT  0
#define OFF_SPROJ (NE)
#define OFF_PNN   (NE + 8 * NN)
#define OFF_DEG   (NE + 16 * NN)
#define OFF_START (NE + 17 * NN)
#define OFF_H4C   (NE + 18 * NN)
#define OFF_GS    (NE + 22 * NN)
#define GS_ESUM1 0
#define GS_NSUM1 512
#define GS_ESUM2 1536
#define GS_NSUM2 2048
#define GS_G1    3072
#define GS_GPE   3328
#define GS_GPN   3840

__global__ __launch_bounds__(512) void k_scatter4(
    const float* __restrict__ ef, const int* __restrict__ snd, const int* __restrict__ rcv,
    const int* __restrict__ h4c, u32* __restrict__ edat)
{
    __shared__ int cur[NPG];
    const int g = blockIdx.x >> 2, c = blockIdx.x & 3;
    const int* cb = h4c + (size_t)(g * 4 + c) * NPG;
    for (int i = threadIdx.x; i < NPG; i += 512) cur[i] = cb[i];
    __syncthreads();
    const int base = g * EPG + c * EPC;
    for (int t = threadIdx.x; t < EPC; t += 512) {
        const int e = base + t;
        const int r = rcv[e] - g * NPG;
        const int p = atomicAdd(&cur[r], 1);
        const u32 s = (u32)(snd[e] - g * NPG);
        edat[p] = (s << 16) | (u32)f2bf(ef[e]);
    }
}

__global__ __launch_bounds__(256) void k_node_pre(
    const float* __restrict__ nf,
    const float* __restrict__ Wes, const float* __restrict__ Wnn,
    const float* __restrict__ ebe, const float* __restrict__ ebn,
    __half* __restrict__ sproj, __half* __restrict__ pnn, float* __restrict__ gs)
{
    __shared__ float wE[480], wN[960];
    for (int i = threadIdx.x; i < 480; i += 256) wE[i] = Wes[i];
    for (int i = threadIdx.x; i < 960; i += 256) wN[i] = Wnn[i];
    if (blockIdx.x == 0) {
        for (int i = threadIdx.x; i < 3072; i += 256) gs[i] = 0.f;
    }
    __syncthreads();
    const int v = blockIdx.x * 256 + threadIdx.x;
    const float4* row = reinterpret_cast<const float4*>(nf + (size_t)v * 60);
    float x[60];
#pragma unroll
    for (int i = 0; i < 15; ++i) {
        const float4 a = row[i];
        x[4 * i] = a.x; x[4 * i + 1] = a.y; x[4 * i + 2] = a.z; x[4 * i + 3] = a.w;
    }
    float pes[8], pn[16];
#pragma unroll
    for (int j = 0; j < 8; ++j) pes[j] = ebe[j];
#pragma unroll
    for (int j = 0; j < 16; ++j) pn[j] = ebn[j];
#pragma unroll
    for (int k = 0; k < 60; ++k) {
        const float xv = x[k];
#pragma unroll
        for (int j = 0; j < 8; ++j)  pes[j] = fmaf(xv, wE[j * 60 + k], pes[j]);
#pragma unroll
        for (int j = 0; j < 16; ++j) pn[j]  = fmaf(xv, wN[j * 60 + k], pn[j]);
    }
    H8* sp = reinterpret_cast<H8*>(sproj) + (size_t)v * 2;
    sp[0] = pack8(pes);
    H8* pp = reinterpret_cast<H8*>(pnn) + (size_t)v * 2;
    pp[0] = pack8(pn); pp[1] = pack8(pn + 8);
}

__global__ __launch_bounds__(256) void k_enc(
    const int* __restrict__ deg, const int* __restrict__ start, const u32* __restrict__ edat,
    __half* __restrict__ sproj, __half* __restrict__ pnn,
    const float* __restrict__ eWee,
    const float* __restrict__ eWni,
    const float* __restrict__ hWes, const float* __restrict__ hWnn,
    float* __restrict__ esum, float* __restrict__ nsum)
{
    __shared__ float wNI[128], wES[128], wNN2[256];
    for (int i = threadIdx.x; i < 128; i += 256) { wNI[i] = eWni[i]; wES[i] = hWes[i]; }
    wNN2[threadIdx.x] = hWnn[threadIdx.x];
    __syncthreads();
    const int t = blockIdx.x * 256 + threadIdx.x;
    const int v = t >> 1, h = t & 1;
    const int g = v / NPG;
    float wee[8];
#pragma unroll
    for (int j = 0; j < 8; ++j) wee[j] = eWee[j];
    const int dg = deg[v];
    const int st = start[v];
    const int half0 = dg >> 1;
    int i = st + (h ? half0 : 0);
    const int iend = st + (h ? dg : half0);
    float m[8];
#pragma unroll
    for (int j = 0; j < 8; ++j) m[j] = 0.f;
    const H8* hb = reinterpret_cast<const H8*>(sproj) + (size_t)g * NPG * 2;

#define ENC_EDGE(W, A) { \
    const float f_ = __uint_as_float(((W) & 0xffffu) << 16); \
    float pv_[8]; unpack8((A), pv_); \
    _Pragma("unroll") \
    for (int j = 0; j < 8; ++j) m[j] += fmaxf(0.f, fmaf(f_, wee[j], pv_[j])); }

    for (; i + 4 <= iend; i += 4) {
        const u32 w0 = edat[i], w1 = edat[i + 1], w2v = edat[i + 2], w3v = edat[i + 3];
        const H8 A0 = hb[(size_t)(w0 >> 16) * 2];
        const H8 A1 = hb[(size_t)(w1 >> 16) * 2];
        const H8 A2 = hb[(size_t)(w2v >> 16) * 2];
        const H8 A3 = hb[(size_t)(w3v >> 16) * 2];
        ENC_EDGE(w0, A0) ENC_EDGE(w1, A1) ENC_EDGE(w2v, A2) ENC_EDGE(w3v, A3)
    }
    for (; i < iend; ++i) {
        const u32 w = edat[i];
        const H8 A = hb[(size_t)(w >> 16) * 2];
        ENC_EDGE(w, A)
    }
#undef ENC_EDGE

#pragma unroll
    for (int j = 0; j < 8; ++j) m[j] += __shfl_xor(m[j], 1);
#pragma unroll
    for (int j = 0; j < 8; ++j) {
        const float s = wsum_par(m[j]);
        if ((threadIdx.x & 63) == 0) atomicAdd(&esum[g * 8 + j], s);
    }
    const float ic = 1.f / fmaxf((float)dg, 1.f);
    float mk[8];
#pragma unroll
    for (int k = 0; k < 8; ++k) mk[k] = m[k] * ic;
    const H8* pp = reinterpret_cast<const H8*>(pnn) + (size_t)v * 2;
    float pn8[8]; unpack8(pp[h], pn8);
    float n1[8];
#pragma unroll
    for (int jj = 0; jj < 8; ++jj) {
        float x = pn8[jj];
#pragma unroll
        for (int k = 0; k < 8; ++k) x = fmaf(mk[k], wNI[(h * 8 + jj) * 8 + k], x);
        n1[jj] = fmaxf(0.f, x);
    }
    float n1o[8];
#pragma unroll
    for (int jj = 0; jj < 8; ++jj) n1o[jj] = __shfl_xor(n1[jj], 1);
    float full[16];
#pragma unroll
    for (int jj = 0; jj < 8; ++jj) {
        full[jj]     = h ? n1o[jj] : n1[jj];
        full[8 + jj] = h ? n1[jj]  : n1o[jj];
    }
    float pe4[4];
#pragma unroll
    for (int oo = 0; oo < 4; ++oo) {
        const int o = h * 4 + oo;
        float x = 0.f;
#pragma unroll
        for (int j = 0; j < 16; ++j) x = fmaf(full[j], wES[o * 16 + j], x);
        pe4[oo] = x;
    }
    *reinterpret_cast<H4*>(sproj + (size_t)v * 16 + 8 + h * 4) = pack4(pe4);
    float pw8[8];
#pragma unroll
    for (int oo = 0; oo < 8; ++oo) {
        const int o = h * 8 + oo;
        float x = 0.f;
#pragma unroll
        for (int j = 0; j < 16; ++j) x = fmaf(full[j], wNN2[o * 16 + j], x);
        pw8[oo] = x;
    }
    reinterpret_cast<H8*>(pnn)[(size_t)v * 2 + h] = pack8(pw8);
#pragma unroll
    for (int jj = 0; jj < 8; ++jj) {
        const float s = wsum_par(n1[jj]);
        if ((threadIdx.x & 63) == h) atomicAdd(&nsum[g * 16 + h * 8 + jj], s);
    }
}

__global__ __launch_bounds__(256) void k_hid(
    const int* __restrict__ deg, const int* __restrict__ start, const u32* __restrict__ edat,
    const __half* __restrict__ sproj, const __half* __restrict__ pnn,
    const float* __restrict__ eWee,
    const float* __restrict__ hWee, const float* __restrict__ hbe, const float* __restrict__ gpe,
    const float* __restrict__ hWni, const float* __restrict__ hbn, const float* __restrict__ gpn,
    const float* __restrict__ roWn, const float* __restrict__ robn,
    float* __restrict__ esum, float* __restrict__ nsum, float* __restrict__ outn)
{
    __shared__ float w2[64], wNI[128], rW[16];
    for (int i = threadIdx.x; i < 128; i += 256) wNI[i] = hWni[i];
    if (threadIdx.x < 64) w2[threadIdx.x] = hWee[threadIdx.x];
    if (threadIdx.x < 16) rW[threadIdx.x] = roWn[threadIdx.x];
    __syncthreads();
    const int t = blockIdx.x * 256 + threadIdx.x;
    const int v = t >> 1, h = t & 1;
    const int g = v / NPG;
    float wee[8], add2[8];
#pragma unroll
    for (int j = 0; j < 8; ++j) { wee[j] = eWee[j]; add2[j] = gpe[g * 8 + j] + hbe[j]; }
    const int dg = deg[v];
    const int st = start[v];
    const int half0 = dg >> 1;
    int i = st + (h ? half0 : 0);
    const int iend = st + (h ? dg : half0);
    float m2[8];
#pragma unroll
    for (int j = 0; j < 8; ++j) m2[j] = 0.f;
    const H8* hb = reinterpret_cast<const H8*>(sproj) + (size_t)g * NPG * 2;

#define HID_EDGE(W, A, B) { \
    const float f_ = __uint_as_float(((W) & 0xffffu) << 16); \
    float pv_[8], qv_[8]; unpack8((A), pv_); unpack8((B), qv_); \
    float e1_[8]; \
    _Pragma("unroll") \
    for (int j = 0; j < 8; ++j) e1_[j] = fmaxf(0.f, fmaf(f_, wee[j], pv_[j])); \
    _Pragma("unroll") \
    for (int j = 0; j < 8; ++j) { \
        float x_ = qv_[j] + add2[j]; \
        _Pragma("unroll") \
        for (int k = 0; k < 8; ++k) x_ = fmaf(e1_[k], w2[j * 8 + k], x_); \
        m2[j] += fmaxf(0.f, x_); } }

    for (; i + 4 <= iend; i += 4) {
        const u32 w0 = edat[i], w1 = edat[i + 1], w2v = edat[i + 2], w3v = edat[i + 3];
        const size_t s0 = (size_t)(w0 >> 16) * 2, s1 = (size_t)(w1 >> 16) * 2;
        const size_t s2 = (size_t)(w2v >> 16) * 2, s3 = (size_t)(w3v >> 16) * 2;
        const H8 A0 = hb[s0], B0 = hb[s0 + 1];
        const H8 A1 = hb[s1], B1 = hb[s1 + 1];
        const H8 A2 = hb[s2], B2 = hb[s2 + 1];
        const H8 A3 = hb[s3], B3 = hb[s3 + 1];
        HID_EDGE(w0, A0, B0) HID_EDGE(w1, A1, B1) HID_EDGE(w2v, A2, B2) HID_EDGE(w3v, A3, B3)
    }
    for (; i < iend; ++i) {
        const u32 w = edat[i];
        const size_t s = (size_t)(w >> 16) * 2;
        const H8 A = hb[s], B = hb[s + 1];
        HID_EDGE(w, A, B)
    }
#undef HID_EDGE

#pragma unroll
    for (int j = 0; j < 8; ++j) m2[j] += __shfl_xor(m2[j], 1);
#pragma unroll
    for (int j = 0; j < 8; ++j) {
        const float s = wsum_par(m2[j]);
        if ((threadIdx.x & 63) == 0) atomicAdd(&esum[g * 8 + j], s);
    }
    const float ic = 1.f / fmaxf((float)dg, 1.f);
    float mk[8];
#pragma unroll
    for (int k = 0; k < 8; ++k) mk[k] = m2[k] * ic;
    const H8* pp = reinterpret_cast<const H8*>(pnn) + (size_t)v * 2;
    float pn8[8]; unpack8(pp[h], pn8);
    float zp = 0.f;
    float n2[8];
#pragma unroll
    for (int jj = 0; jj < 8; ++jj) {
        const int j = h * 8 + jj;
        float x = pn8[jj] + gpn[g * 16 + j] + hbn[j];
#pragma unroll
        for (int k = 0; k < 8; ++k) x = fmaf(mk[k], wNI[j * 8 + k], x);
        n2[jj] = fmaxf(0.f, x);
        zp = fmaf(n2[jj], rW[j], zp);
    }
    const float z = zp + __shfl_xor(zp, 1);
    if (h == 0) outn[v] = sigmoidf_(z + robn[0]);
#pragma unroll
    for (int jj = 0; jj < 8; ++jj) {
        const float s = wsum_par(n2[jj]);
        if ((threadIdx.x & 63) == h) atomicAdd(&nsum[g * 16 + h * 8 + jj], s);
    }
}

// ============================ LAUNCH ============================

extern "C" void kernel_launch(void* const* d_in, const int* in_sizes, int n_in,
                              void* d_out, int out_size, void* d_ws, size_t ws_size,
                              hipStream_t stream)
{
    const float* nf   = (const float*)d_in[0];
    const float* ef   = (const float*)d_in[1];
    const int*   snd  = (const int*)d_in[2];
    const int*   rcv  = (const int*)d_in[3];
    const float* eWee = (const float*)d_in[6];
    const float* eWes = (const float*)d_in[7];
    const float* ebe  = (const float*)d_in[8];
    const float* eWnn = (const float*)d_in[9];
    const float* eWni = (const float*)d_in[10];
    const float* ebn  = (const float*)d_in[11];
    const float* eWge = (const float*)d_in[12];
    const float* eWgn = (const float*)d_in[13];
    const float* ebg  = (const float*)d_in[14];
    const float* hWee = (const float*)d_in[15];
    const float* hWes = (const float*)d_in[16];
    const float* hWeg = (const float*)d_in[17];
    const float* hbe  = (const float*)d_in[18];
    const float* hWnn = (const float*)d_in[19];
    const float* hWni = (const float*)d_in[20];
    const float* hWng = (const float*)d_in[21];
    const float* hbn  = (const float*)d_in[22];
    const float* hWge = (const float*)d_in[23];
    const float* hWgn = (const float*)d_in[24];
    const float* hWgg = (const float*)d_in[25];
    const float* hbg  = (const float*)d_in[26];
    const float* roWn = (const float*)d_in[27];
    const float* robn = (const float*)d_in[28];
    const float* roWg = (const float*)d_in[29];
    const float* robg = (const float*)d_in[30];

    float* ws  = (float*)d_ws;
    float* out = (float*)d_out;

    if (ws_size >= P2_NEED_BYTES) {
        // ---- NEW PATH: sender-major scatter-store, zero gathers ----
        u32*    edat_s  = (u32*)(ws + P2_EDATS);
        int*    deg_r   = (int*)(ws + P2_DEGR);
        int*    startLr = (int*)(ws + P2_STARTR);
        int*    deg_s   = (int*)(ws + P2_DEGS);
        int*    start_s = (int*)(ws + P2_STARTS);
        __half* sprojA  = (__half*)(ws + P2_SPROJA);
        __half* pnn     = (__half*)(ws + P2_PNN);
        float*  gs      = ws + P2_GS;
        int*    rpos    = (int*)(ws + P2_POOL);
        int*    h4c_r   = (int*)(ws + P2_POOL + NE);
        int*    h4c_s   = (int*)(ws + P2_POOL + NE + 4 * NN);
        __half* evals   = (__half*)(ws + P2_POOL);
        float* esum1 = gs + GS_ESUM1;
        float* nsum1 = gs + GS_NSUM1;
        float* esum2 = gs + GS_ESUM2;
        float* nsum2 = gs + GS_NSUM2;
        float* g1    = gs + GS_G1;
        float* gpe   = gs + GS_GPE;
        float* gpn   = gs + GS_GPN;

        k_hist4<<<NG * 4, 512, 0, stream>>>(rcv, h4c_r);
        n_scan_local<<<NG, 320, 0, stream>>>(h4c_r, deg_r, startLr);
        n_scat_rpos<<<NG * 4, 512, 0, stream>>>(rcv, h4c_r, rpos);
        k_hist4<<<NG * 4, 512, 0, stream>>>(snd, h4c_s);
        k_scan<<<NG, 320, 0, stream>>>(h4c_s, deg_s, start_s);
        n_scat_s<<<NG * 4, 512, 0, stream>>>(ef, snd, rpos, h4c_s, edat_s);
        n_node_pre<<<NN / 256, 256, 0, stream>>>(nf, eWes, eWnn, ebe, ebn, sprojA, pnn, gs);
        n_a1<<<NN / 256, 256, 0, stream>>>(deg_s, start_s, edat_s, sprojA, eWee, evals);
        n_b1<<<NN / 256, 256, 0, stream>>>(deg_r, startLr, evals, pnn, eWni, esum1, nsum1);
        k_glob_enc<<<1, 64, 0, stream>>>(esum1, nsum1, eWge, eWgn, ebg, hWeg, hWng, g1, gpe, gpn);
        n_a2<<<NN / 256, 256, 0, stream>>>(deg_s, start_s, edat_s, sprojA, pnn,
                                           eWee, hWes, hWee, hbe, gpe, evals);
        n_b2<<<NN / 256, 256, 0, stream>>>(deg_r, startLr, evals, pnn, hWnn, hWni, hbn, gpn,
                                           roWn, robn, esum2, nsum2, out);
        k_glob_hid<<<1, 64, 0, stream>>>(esum2, nsum2, g1, hWge, hWgn, hWgg, hbg, roWg, robg, out + NN);
    } else {
        // ---- OLD PATH (R8): gather-based, 15.6 MB ws ----
        u32*    edat  = (u32*)(ws + OFF_EDAT);
        __half* sproj = (__half*)(ws + OFF_SPROJ);
        __half* pnn   = (__half*)(ws + OFF_PNN);
        int*    deg   = (int*)(ws + OFF_DEG);
        int*    start = (int*)(ws + OFF_START);
        int*    h4c   = (int*)(ws + OFF_H4C);
        float*  gs    = ws + OFF_GS;
        float* esum1 = gs + GS_ESUM1;
        float* nsum1 = gs + GS_NSUM1;
        float* esum2 = gs + GS_ESUM2;
        float* nsum2 = gs + GS_NSUM2;
        float* g1    = gs + GS_G1;
        float* gpe   = gs + GS_GPE;
        float* gpn   = gs + GS_GPN;

        k_hist4<<<NG * 4, 512, 0, stream>>>(rcv, h4c);
        k_scan<<<NG, 320, 0, stream>>>(h4c, deg, start);
        k_scatter4<<<NG * 4, 512, 0, stream>>>(ef, snd, rcv, h4c, edat);
        k_node_pre<<<NN / 256, 256, 0, stream>>>(nf, eWes, eWnn, ebe, ebn, sproj, pnn, gs);
        k_enc<<<NN * 2 / 256, 256, 0, stream>>>(deg, start, edat, sproj, pnn,
                                                eWee, eWni, hWes, hWnn, esum1, nsum1);
        k_glob_enc<<<1, 64, 0, stream>>>(esum1, nsum1, eWge, eWgn, ebg, hWeg, hWng, g1, gpe, gpn);
        k_hid<<<NN * 2 / 256, 256, 0, stream>>>(deg, start, edat, sproj, pnn,
                                                eWee, hWee, hbe, gpe, hWni, hbn, gpn,
                                                roWn, robn, esum2, nsum2, out);
        k_glob_hid<<<1, 64, 0, stream>>>(esum2, nsum2, g1, hWge, hWgn, hWgg, hbg, roWg, robg, out + NN);
    }
}

// Round 11
// 190.521 us; speedup vs baseline: 1.0228x; 1.0228x over previous
//
#include <hip/hip_runtime.h>
#include <hip/hip_bf16.h>
#include <hip/hip_fp16.h>

#define NN   102400
#define NG   64
#define NPG  1600
#define NE   1638400
#define EPG  25600
#define EPC  (EPG / 4)

typedef unsigned int u32;
typedef unsigned short u16;

// ---- workspace layout (float offsets), ~15.6 MB (< 16.8 MB proven safe) ----
#define OFF_EDAT  0                       // u32[NE]: (sender_local<<16) | bf16(ef), receiver-sorted
#define OFF_SPROJ (NE)                    // __half[NN*16]: [0..8)=enc p_es+ebe, [8..16)=pes2
#define OFF_PNN   (NE + 8 * NN)           // __half[NN*16]: p_nn+ebn -> n1@hWnn^T
#define OFF_DEG   (NE + 16 * NN)          // int[NN]
#define OFF_START (NE + 17 * NN)          // int[NN]
#define OFF_H4C   (NE + 18 * NN)          // int[4*NN]
#define OFF_GS    (NE + 22 * NN)          // 4864 floats
#define OFF_CNT   (NE + 22 * NN + 4864)   // int[2]: completion counters
#define GS_ESUM1 0
#define GS_NSUM1 512
#define GS_ESUM2 1536
#define GS_NSUM2 2048
#define GS_G1    3072
#define GS_GPE   3328
#define GS_GPN   3840

struct H8 { __half2 a, b, c, d; };

__device__ __forceinline__ void unpack8_f4(const float4 v, float* o) {
    const __half2* h = reinterpret_cast<const __half2*>(&v);
    float2 t0 = __half22float2(h[0]), t1 = __half22float2(h[1]);
    float2 t2 = __half22float2(h[2]), t3 = __half22float2(h[3]);
    o[0]=t0.x; o[1]=t0.y; o[2]=t1.x; o[3]=t1.y; o[4]=t2.x; o[5]=t2.y; o[6]=t3.x; o[7]=t3.y;
}
__device__ __forceinline__ void unpack8(const H8 v, float* o) {
    float2 t0 = __half22float2(v.a), t1 = __half22float2(v.b);
    float2 t2 = __half22float2(v.c), t3 = __half22float2(v.d);
    o[0]=t0.x; o[1]=t0.y; o[2]=t1.x; o[3]=t1.y; o[4]=t2.x; o[5]=t2.y; o[6]=t3.x; o[7]=t3.y;
}
__device__ __forceinline__ H8 pack8(const float* v) {
    H8 r;
    r.a = __floats2half2_rn(v[0], v[1]); r.b = __floats2half2_rn(v[2], v[3]);
    r.c = __floats2half2_rn(v[4], v[5]); r.d = __floats2half2_rn(v[6], v[7]);
    return r;
}
__device__ __forceinline__ u16 f2bf(float f) {
    u32 u = __float_as_uint(f);
    return (u16)((u + 0x7fffu + ((u >> 16) & 1u)) >> 16);
}
__device__ __forceinline__ float wsum(float v) {
#pragma unroll
    for (int o = 32; o >= 1; o >>= 1) v += __shfl_xor(v, o);
    return v;
}
__device__ __forceinline__ float sigmoidf_(float x) { return 1.f / (1.f + expf(-x)); }

// H1: per-chunk receiver histogram.
__global__ __launch_bounds__(512) void k_hist4(const int* __restrict__ rcv, int* __restrict__ h4) {
    __shared__ int h[NPG];
    const int g = blockIdx.x >> 2, c = blockIdx.x & 3;
    for (int i = threadIdx.x; i < NPG; i += 512) h[i] = 0;
    __syncthreads();
    const int base = g * EPG + c * EPC;
    for (int t = threadIdx.x; t < EPC; t += 512) atomicAdd(&h[rcv[base + t] - g * NPG], 1);
    __syncthreads();
    int* out = h4 + (size_t)(g * 4 + c) * NPG;
    for (int i = threadIdx.x; i < NPG; i += 512) out[i] = h[i];
}

// H2: per-graph scan; also zeroes the completion counters.
__global__ __launch_bounds__(320) void k_scan(
    int* __restrict__ h4c, int* __restrict__ deg, int* __restrict__ start, int* __restrict__ cnt)
{
    if (blockIdx.x == 0 && threadIdx.x == 0) { cnt[0] = 0; cnt[1] = 0; }
    __shared__ int part[320];
    const int g = blockIdx.x, tid = threadIdx.x;
    const int vb = tid * 5;
    int hc[5][4], d[5], pre[5];
    int ts = 0;
#pragma unroll
    for (int i = 0; i < 5; ++i) {
        const int v = vb + i;
#pragma unroll
        for (int c = 0; c < 4; ++c) hc[i][c] = h4c[(size_t)(g * 4 + c) * NPG + v];
        d[i] = hc[i][0] + hc[i][1] + hc[i][2] + hc[i][3];
        pre[i] = ts;
        ts += d[i];
    }
    part[tid] = ts;
    __syncthreads();
    for (int o = 1; o < 320; o <<= 1) {
        const int v = (tid >= o) ? part[tid - o] : 0;
        __syncthreads();
        part[tid] += v;
        __syncthreads();
    }
    const int off = g * EPG + part[tid] - ts;
#pragma unroll
    for (int i = 0; i < 5; ++i) {
        const int v = vb + i;
        const int st = off + pre[i];
        deg[g * NPG + v] = d[i];
        start[g * NPG + v] = st;
        int run = st;
#pragma unroll
        for (int c = 0; c < 4; ++c) {
            h4c[(size_t)(g * 4 + c) * NPG + v] = run;
            run += hc[i][c];
        }
    }
}

// H3: scatter edges into receiver-sorted order via LDS cursors.
__global__ __launch_bounds__(512) void k_scatter4(
    const float* __restrict__ ef, const int* __restrict__ snd, const int* __restrict__ rcv,
    const int* __restrict__ h4c, u32* __restrict__ edat)
{
    __shared__ int cur[NPG];
    const int g = blockIdx.x >> 2, c = blockIdx.x & 3;
    const int* cb = h4c + (size_t)(g * 4 + c) * NPG;
    for (int i = threadIdx.x; i < NPG; i += 512) cur[i] = cb[i];
    __syncthreads();
    const int base = g * EPG + c * EPC;
    for (int t = threadIdx.x; t < EPC; t += 512) {
        const int e = base + t;
        const int r = rcv[e] - g * NPG;
        const int p = atomicAdd(&cur[r], 1);
        const u32 s = (u32)(snd[e] - g * NPG);
        edat[p] = (s << 16) | (u32)f2bf(ef[e]);
    }
}

// K1: per-node encoder pre-projections; biases folded; zeroes gs sums.
__global__ __launch_bounds__(256) void k_node_pre(
    const float* __restrict__ nf,
    const float* __restrict__ Wes, const float* __restrict__ Wnn,
    const float* __restrict__ ebe, const float* __restrict__ ebn,
    __half* __restrict__ sproj, __half* __restrict__ pnn, float* __restrict__ gs)
{
    __shared__ float wE[480], wN[960];
    for (int i = threadIdx.x; i < 480; i += 256) wE[i] = Wes[i];
    for (int i = threadIdx.x; i < 960; i += 256) wN[i] = Wnn[i];
    if (blockIdx.x == 0) {
        for (int i = threadIdx.x; i < 3072; i += 256) gs[i] = 0.f;
    }
    __syncthreads();
    const int v = blockIdx.x * 256 + threadIdx.x;
    const float4* row = reinterpret_cast<const float4*>(nf + (size_t)v * 60);
    float x[60];
#pragma unroll
    for (int i = 0; i < 15; ++i) {
        const float4 a = row[i];
        x[4 * i] = a.x; x[4 * i + 1] = a.y; x[4 * i + 2] = a.z; x[4 * i + 3] = a.w;
    }
    float pes[8], pn[16];
#pragma unroll
    for (int j = 0; j < 8; ++j) pes[j] = ebe[j];
#pragma unroll
    for (int j = 0; j < 16; ++j) pn[j] = ebn[j];
#pragma unroll
    for (int k = 0; k < 60; ++k) {
        const float xv = x[k];
#pragma unroll
        for (int j = 0; j < 8; ++j)  pes[j] = fmaf(xv, wE[j * 60 + k], pes[j]);
#pragma unroll
        for (int j = 0; j < 16; ++j) pn[j]  = fmaf(xv, wN[j * 60 + k], pn[j]);
    }
    H8* sp = reinterpret_cast<H8*>(sproj) + (size_t)v * 2;
    sp[0] = pack8(pes);
    H8* pp = reinterpret_cast<H8*>(pnn) + (size_t)v * 2;
    pp[0] = pack8(pn); pp[1] = pack8(pn + 8);
}

// K2: encoder edge gather (whole-node batched) + node layer + fused global layer.
__global__ __launch_bounds__(256) void k_enc2(
    const int* __restrict__ deg, const int* __restrict__ start, const u32* __restrict__ edat,
    __half* __restrict__ sproj, __half* __restrict__ pnn,
    const float* __restrict__ eWee, const float* __restrict__ eWni,
    const float* __restrict__ hWes, const float* __restrict__ hWnn,
    float* __restrict__ esum, float* __restrict__ nsum,
    const float* __restrict__ eWge, const float* __restrict__ eWgn, const float* __restrict__ ebg,
    const float* __restrict__ hWeg, const float* __restrict__ hWng,
    float* __restrict__ g1, float* __restrict__ gpe, float* __restrict__ gpn,
    int* __restrict__ cnt)
{
    __shared__ float wNI[128], wES[128], wNN2[256];
    __shared__ int lastFlag;
    for (int i = threadIdx.x; i < 128; i += 256) { wNI[i] = eWni[i]; wES[i] = hWes[i]; }
    wNN2[threadIdx.x] = hWnn[threadIdx.x];
    __syncthreads();
    const int v = blockIdx.x * 256 + threadIdx.x;
    const int g = v / NPG;   // wave-uniform (1600 % 64 == 0)
    float wee[8];
#pragma unroll
    for (int j = 0; j < 8; ++j) wee[j] = eWee[j];
    const int dg = deg[v];
    const int st = start[v];
    float m[8];
#pragma unroll
    for (int j = 0; j < 8; ++j) m[j] = 0.f;
    const float4* hb4 = reinterpret_cast<const float4*>(sproj) + (size_t)g * NPG * 2;

    for (int base = 0; base < dg; base += 16) {
        u32 w[16];
#pragma unroll
        for (int j = 0; j < 16; ++j) {
            const int idx = base + j;
            w[j] = edat[st + (idx < dg ? idx : 0)];
        }
        float4 A[16];
#pragma unroll
        for (int j = 0; j < 16; ++j) A[j] = hb4[(size_t)(w[j] >> 16) * 2];
#pragma unroll
        for (int j = 0; j < 16; ++j) {
            const float val = (base + j < dg) ? 1.f : 0.f;
            const float f = __uint_as_float((w[j] & 0xffffu) << 16);
            float pv[8]; unpack8_f4(A[j], pv);
#pragma unroll
            for (int k = 0; k < 8; ++k) m[k] += val * fmaxf(0.f, fmaf(f, wee[k], pv[k]));
        }
    }
#pragma unroll
    for (int j = 0; j < 8; ++j) {
        const float s = wsum(m[j]);
        if ((threadIdx.x & 63) == 0) atomicAdd(&esum[g * 8 + j], s);
    }
    const float ic = 1.f / fmaxf((float)dg, 1.f);
    float mk[8];
#pragma unroll
    for (int k = 0; k < 8; ++k) mk[k] = m[k] * ic;
    H8* pp = reinterpret_cast<H8*>(pnn) + (size_t)v * 2;
    float pn[16]; unpack8(pp[0], pn); unpack8(pp[1], pn + 8);
    float n1[16];
#pragma unroll
    for (int j = 0; j < 16; ++j) {
        float x = pn[j];
#pragma unroll
        for (int k = 0; k < 8; ++k) x = fmaf(mk[k], wNI[j * 8 + k], x);
        n1[j] = fmaxf(0.f, x);
    }
    float pe[8];
#pragma unroll
    for (int o = 0; o < 8; ++o) {
        float x = 0.f;
#pragma unroll
        for (int j = 0; j < 16; ++j) x = fmaf(n1[j], wES[o * 16 + j], x);
        pe[o] = x;
    }
    reinterpret_cast<H8*>(sproj)[(size_t)v * 2 + 1] = pack8(pe);
    float pw[16];
#pragma unroll
    for (int o = 0; o < 16; ++o) {
        float x = 0.f;
#pragma unroll
        for (int j = 0; j < 16; ++j) x = fmaf(n1[j], wNN2[o * 16 + j], x);
        pw[o] = x;
    }
    pp[0] = pack8(pw); pp[1] = pack8(pw + 8);
#pragma unroll
    for (int j = 0; j < 16; ++j) {
        const float s = wsum(n1[j]);
        if ((threadIdx.x & 63) == 0) atomicAdd(&nsum[g * 16 + j], s);
    }

    // ---- fused encoder-global tail (last block) ----
    __threadfence();
    __syncthreads();
    if (threadIdx.x == 0) {
        const int old = atomicAdd(&cnt[0], 1);
        lastFlag = (old == (int)gridDim.x - 1);
    }
    __syncthreads();
    if (lastFlag && threadIdx.x < NG) {
        const int gg = threadIdx.x;
        float es[8], ns[16];
#pragma unroll
        for (int k = 0; k < 8; ++k)  es[k] = atomicAdd(&esum[gg * 8 + k], 0.f) * (1.f / EPG);
#pragma unroll
        for (int k = 0; k < 16; ++k) ns[k] = atomicAdd(&nsum[gg * 16 + k], 0.f) * (1.f / NPG);
        float gv[4];
#pragma unroll
        for (int o = 0; o < 4; ++o) {
            float x = ebg[o];
#pragma unroll
            for (int k = 0; k < 8; ++k)  x = fmaf(es[k], eWge[o * 8 + k], x);
#pragma unroll
            for (int k = 0; k < 16; ++k) x = fmaf(ns[k], eWgn[o * 16 + k], x);
            gv[o] = fmaxf(0.f, x);
            g1[gg * 4 + o] = gv[o];
        }
#pragma unroll
        for (int j = 0; j < 8; ++j) {
            float x = 0.f;
#pragma unroll
            for (int o = 0; o < 4; ++o) x = fmaf(gv[o], hWeg[j * 4 + o], x);
            gpe[gg * 8 + j] = x;
        }
#pragma unroll
        for (int j = 0; j < 16; ++j) {
            float x = 0.f;
#pragma unroll
            for (int o = 0; o < 4; ++o) x = fmaf(gv[o], hWng[j * 4 + o], x);
            gpn[gg * 16 + j] = x;
        }
    }
}

// K3: hidden edge gather (batched A+B) + node layer + readout + fused hidden-global tail.
__global__ __launch_bounds__(256) void k_hid2(
    const int* __restrict__ deg, const int* __restrict__ start, const u32* __restrict__ edat,
    const __half* __restrict__ sproj, const __half* __restrict__ pnn,
    const float* __restrict__ eWee,
    const float* __restrict__ hWee, const float* __restrict__ hbe, const float* __restrict__ gpe,
    const float* __restrict__ hWni, const float* __restrict__ hbn, const float* __restrict__ gpn,
    const float* __restrict__ roWn, const float* __restrict__ robn,
    float* __restrict__ esum, float* __restrict__ nsum, float* __restrict__ outn,
    const float* __restrict__ g1,
    const float* __restrict__ hWge, const float* __restrict__ hWgn,
    const float* __restrict__ hWgg, const float* __restrict__ hbg,
    const float* __restrict__ roWg, const float* __restrict__ robg,
    float* __restrict__ outg, int* __restrict__ cnt)
{
    __shared__ float w2[64], wNI[128], rW[16];
    __shared__ int lastFlag;
    for (int i = threadIdx.x; i < 128; i += 256) wNI[i] = hWni[i];
    if (threadIdx.x < 64) w2[threadIdx.x] = hWee[threadIdx.x];
    if (threadIdx.x < 16) rW[threadIdx.x] = roWn[threadIdx.x];
    __syncthreads();
    const int v = blockIdx.x * 256 + threadIdx.x;
    const int g = v / NPG;
    float wee[8], add2[8];
#pragma unroll
    for (int j = 0; j < 8; ++j) { wee[j] = eWee[j]; add2[j] = gpe[g * 8 + j] + hbe[j]; }
    const int dg = deg[v];
    const int st = start[v];
    float m2[8];
#pragma unroll
    for (int j = 0; j < 8; ++j) m2[j] = 0.f;
    const float4* hb4 = reinterpret_cast<const float4*>(sproj) + (size_t)g * NPG * 2;

    for (int base = 0; base < dg; base += 8) {
        u32 w[8];
#pragma unroll
        for (int j = 0; j < 8; ++j) {
            const int idx = base + j;
            w[j] = edat[st + (idx < dg ? idx : 0)];
        }
        float4 A[8], B[8];
#pragma unroll
        for (int j = 0; j < 8; ++j) {
            const size_t s2 = (size_t)(w[j] >> 16) * 2;
            A[j] = hb4[s2]; B[j] = hb4[s2 + 1];
        }
#pragma unroll
        for (int j = 0; j < 8; ++j) {
            const float val = (base + j < dg) ? 1.f : 0.f;
            const float f = __uint_as_float((w[j] & 0xffffu) << 16);
            float pv[8], qv[8];
            unpack8_f4(A[j], pv); unpack8_f4(B[j], qv);
            float e1[8];
#pragma unroll
            for (int k = 0; k < 8; ++k) e1[k] = fmaxf(0.f, fmaf(f, wee[k], pv[k]));
#pragma unroll
            for (int k = 0; k < 8; ++k) {
                float x = qv[k] + add2[k];
#pragma unroll
                for (int kk = 0; kk < 8; ++kk) x = fmaf(e1[kk], w2[k * 8 + kk], x);
                m2[k] += val * fmaxf(0.f, x);
            }
        }
    }
#pragma unroll
    for (int j = 0; j < 8; ++j) {
        const float s = wsum(m2[j]);
        if ((threadIdx.x & 63) == 0) atomicAdd(&esum[g * 8 + j], s);
    }
    const float ic = 1.f / fmaxf((float)dg, 1.f);
    float mk[8];
#pragma unroll
    for (int k = 0; k < 8; ++k) mk[k] = m2[k] * ic;
    const H8* pp = reinterpret_cast<const H8*>(pnn) + (size_t)v * 2;
    float pn[16]; unpack8(pp[0], pn); unpack8(pp[1], pn + 8);
    float z = robn[0];
    float n2[16];
#pragma unroll
    for (int j = 0; j < 16; ++j) {
        float x = pn[j] + gpn[g * 16 + j] + hbn[j];
#pragma unroll
        for (int k = 0; k < 8; ++k) x = fmaf(mk[k], wNI[j * 8 + k], x);
        n2[j] = fmaxf(0.f, x);
        z = fmaf(n2[j], rW[j], z);
    }
    outn[v] = sigmoidf_(z);
#pragma unroll
    for (int j = 0; j < 16; ++j) {
        const float s = wsum(n2[j]);
        if ((threadIdx.x & 63) == 0) atomicAdd(&nsum[g * 16 + j], s);
    }

    // ---- fused hidden-global tail (last block) ----
    __threadfence();
    __syncthreads();
    if (threadIdx.x == 0) {
        const int old = atomicAdd(&cnt[1], 1);
        lastFlag = (old == (int)gridDim.x - 1);
    }
    __syncthreads();
    if (lastFlag && threadIdx.x < NG) {
        const int gg = threadIdx.x;
        float es[8], ns[16];
#pragma unroll
        for (int k = 0; k < 8; ++k)  es[k] = atomicAdd(&esum[gg * 8 + k], 0.f) * (1.f / EPG);
#pragma unroll
        for (int k = 0; k < 16; ++k) ns[k] = atomicAdd(&nsum[gg * 16 + k], 0.f) * (1.f / NPG);
        float gv[4];
#pragma unroll
        for (int o = 0; o < 4; ++o) {
            float x = hbg[o];
#pragma unroll
            for (int k = 0; k < 8; ++k)  x = fmaf(es[k], hWge[o * 8 + k], x);
#pragma unroll
            for (int k = 0; k < 16; ++k) x = fmaf(ns[k], hWgn[o * 16 + k], x);
#pragma unroll
            for (int k = 0; k < 4; ++k)  x = fmaf(g1[gg * 4 + k], hWgg[o * 4 + k], x);
            gv[o] = fmaxf(0.f, x);
        }
        float zz = robg[0];
#pragma unroll
        for (int o = 0; o < 4; ++o) zz = fmaf(gv[o], roWg[o], zz);
        outg[gg] = sigmoidf_(zz);
    }
}

extern "C" void kernel_launch(void* const* d_in, const int* in_sizes, int n_in,
                              void* d_out, int out_size, void* d_ws, size_t ws_size,
                              hipStream_t stream)
{
    const float* nf   = (const float*)d_in[0];
    const float* ef   = (const float*)d_in[1];
    const int*   snd  = (const int*)d_in[2];
    const int*   rcv  = (const int*)d_in[3];
    const float* eWee = (const float*)d_in[6];
    const float* eWes = (const float*)d_in[7];
    const float* ebe  = (const float*)d_in[8];
    const float* eWnn = (const float*)d_in[9];
    const float* eWni = (const float*)d_in[10];
    const float* ebn  = (const float*)d_in[11];
    const float* eWge = (const float*)d_in[12];
    const float* eWgn = (const float*)d_in[13];
    const float* ebg  = (const float*)d_in[14];
    const float* hWee = (const float*)d_in[15];
    const float* hWes = (const float*)d_in[16];
    const float* hWeg = (const float*)d_in[17];
    const float* hbe  = (const float*)d_in[18];
    const float* hWnn = (const float*)d_in[19];
    const float* hWni = (const float*)d_in[20];
    const float* hWng = (const float*)d_in[21];
    const float* hbn  = (const float*)d_in[22];
    const float* hWge = (const float*)d_in[23];
    const float* hWgn = (const float*)d_in[24];
    const float* hWgg = (const float*)d_in[25];
    const float* hbg  = (const float*)d_in[26];
    const float* roWn = (const float*)d_in[27];
    const float* robn = (const float*)d_in[28];
    const float* roWg = (const float*)d_in[29];
    const float* robg = (const float*)d_in[30];

    float*  ws    = (float*)d_ws;
    u32*    edat  = (u32*)(ws + OFF_EDAT);
    __half* sproj = (__half*)(ws + OFF_SPROJ);
    __half* pnn   = (__half*)(ws + OFF_PNN);
    int*    deg   = (int*)(ws + OFF_DEG);
    int*    start = (int*)(ws + OFF_START);
    int*    h4c   = (int*)(ws + OFF_H4C);
    float*  gs    = ws + OFF_GS;
    int*    cnt   = (int*)(ws + OFF_CNT);
    float* esum1 = gs + GS_ESUM1;
    float* nsum1 = gs + GS_NSUM1;
    float* esum2 = gs + GS_ESUM2;
    float* nsum2 = gs + GS_NSUM2;
    float* g1    = gs + GS_G1;
    float* gpe   = gs + GS_GPE;
    float* gpn   = gs + GS_GPN;
    float* out   = (float*)d_out;

    k_hist4<<<NG * 4, 512, 0, stream>>>(rcv, h4c);
    k_scan<<<NG, 320, 0, stream>>>(h4c, deg, start, cnt);
    k_scatter4<<<NG * 4, 512, 0, stream>>>(ef, snd, rcv, h4c, edat);
    k_node_pre<<<NN / 256, 256, 0, stream>>>(nf, eWes, eWnn, ebe, ebn, sproj, pnn, gs);
    k_enc2<<<NN / 256, 256, 0, stream>>>(deg, start, edat, sproj, pnn,
                                         eWee, eWni, hWes, hWnn, esum1, nsum1,
                                         eWge, eWgn, ebg, hWeg, hWng, g1, gpe, gpn, cnt);
    k_hid2<<<NN / 256, 256, 0, stream>>>(deg, start, edat, sproj, pnn,
                                         eWee, hWee, hbe, gpe, hWni, hbn, gpn,
                                         roWn, robn, esum2, nsum2, out,
                                         g1, hWge, hWgn, hWgg, hbg, roWg, robg,
                                         out + NN, cnt);
}